// Round 4
// baseline (501.345 us; speedup 1.0000x reference)
//
#include <hip/hip_runtime.h>
#include <hip/hip_bf16.h>
#include <type_traits>
#include <cstdint>

typedef __bf16 bf16x8 __attribute__((ext_vector_type(8)));
typedef float f32x4 __attribute__((ext_vector_type(4)));
typedef __hip_bfloat16 bf16;

static constexpr int BB = 2, SEQ = 2048, HID = 2048, LAT = 512, NHEAD = 16;
static constexpr int HD = 128, RD = 64, DQK = 192;
static constexpr int MR = BB * SEQ;  // 4096 rows
static constexpr int LDW1 = 1152;    // fused proj-1 output cols
static constexpr int LDKV = 4096;    // [k_C | v]
static constexpr int LDQ3 = 3072;    // [q_C | q_R]

__device__ __forceinline__ float bf2f(bf16 x) { return __bfloat162float(x); }
__device__ __forceinline__ bf16 f2bf(float x) { return __float2bfloat16(x); }

__device__ __forceinline__ void gload16(const void* g, void* l) {
  __builtin_amdgcn_global_load_lds(
      (__attribute__((address_space(1))) void*)(uintptr_t)g,
      (__attribute__((address_space(3))) void*)(uint32_t)(uintptr_t)l,
      16, 0, 0);
}

// ---------------- fused prep: weight transposes + rope tables + h convert ----------------
// zones: [0,9856) weight 32x32 transpose tiles; [9856,10112) rope; [10112,18304) h cvt
__global__ void k_prep(const float* __restrict__ h,
                       const float* __restrict__ Wdkv, const float* __restrict__ Wdq,
                       const float* __restrict__ Wkr, const float* __restrict__ Wuk,
                       const float* __restrict__ Wuv, const float* __restrict__ Wuq,
                       const float* __restrict__ Wqr, const float* __restrict__ Wo,
                       bf16* __restrict__ hb, bf16* __restrict__ wt1, bf16* __restrict__ wt2,
                       bf16* __restrict__ wt3, bf16* __restrict__ woT,
                       float* __restrict__ cosT, float* __restrict__ sinT) {
  __shared__ float tbuf[32][33];
  int blk = blockIdx.x;
  if (blk >= 10112) {  // h fp32->bf16, float4 per thread
    int i = (blk - 10112) * 256 + threadIdx.x;
    float4 v = reinterpret_cast<const float4*>(h)[i];
    bf16* o = hb + (size_t)i * 4;
    o[0] = f2bf(v.x); o[1] = f2bf(v.y); o[2] = f2bf(v.z); o[3] = f2bf(v.w);
    return;
  }
  if (blk >= 9856) {  // rope tables
    int idx = (blk - 9856) * 256 + threadIdx.x;
    int s = idx >> 5, j = idx & 31;
    float freq = powf(10000.0f, -(float)(2 * j) / 64.0f);
    float a = (float)s * freq;
    cosT[idx] = cosf(a);
    sinT[idx] = sinf(a);
    return;
  }
  const float* src; bf16* dst; int K, N, local;
  if (blk < 1024)      { src = Wdkv; dst = wt1;                      K = 2048; N = 512;  local = blk; }
  else if (blk < 2048) { src = Wdq;  dst = wt1 + (size_t)512 * 2048; K = 2048; N = 512;  local = blk - 1024; }
  else if (blk < 2176) { src = Wkr;  dst = wt1 + (size_t)1024 * 2048;K = 2048; N = 64;   local = blk - 2048; }
  else if (blk < 3200) { src = Wuk;  dst = wt2;                      K = 512;  N = 2048; local = blk - 2176; }
  else if (blk < 4224) { src = Wuv;  dst = wt2 + (size_t)2048 * 512; K = 512;  N = 2048; local = blk - 3200; }
  else if (blk < 5248) { src = Wuq;  dst = wt3;                      K = 512;  N = 2048; local = blk - 4224; }
  else if (blk < 5760) { src = Wqr;  dst = wt3 + (size_t)2048 * 512; K = 512;  N = 1024; local = blk - 5248; }
  else                 { src = Wo;   dst = woT;                      K = 2048; N = 2048; local = blk - 5760; }
  int tilesX = N >> 5;
  int tx = local % tilesX, ty = local / tilesX;
  int k0 = ty * 32, n0 = tx * 32;
  int c = threadIdx.x & 31, r0 = threadIdx.x >> 5;
#pragma unroll
  for (int i = 0; i < 32; i += 8) tbuf[r0 + i][c] = src[(size_t)(k0 + r0 + i) * N + n0 + c];
  __syncthreads();
#pragma unroll
  for (int i = 0; i < 32; i += 8)
    dst[(size_t)(n0 + r0 + i) * K + k0 + c] = f2bf(tbuf[c][r0 + i]);
}

// ---------------- GEMM body (m97 structure) ----------------
template <int BM, int BN, typename OutT>
__device__ __forceinline__ void gemm_body(const bf16* __restrict__ A, int lda,
                                          const bf16* __restrict__ BT,
                                          OutT* __restrict__ C, int ldc, int K,
                                          int m0, int n0) {
  constexpr int BK = 32;
  constexpr int WN = BN / 64, NW = (BM / 64) * WN;
  __shared__ alignas(16) bf16 As[BM * BK];
  __shared__ alignas(16) bf16 Bs[BN * BK];
  const int tid = threadIdx.x, wave = tid >> 6, lane = tid & 63;
  const int lr = lane & 15, lk = lane >> 4;
  const int wm = (wave / WN) * 64, wn = (wave % WN) * 64;
  const int srow = lane >> 2;
  const int scol = (lane & 3) * 8;
  f32x4 acc[4][4] = {};
  for (int kt = 0; kt < K; kt += BK) {
    for (int c = wave; c < BM / 16; c += NW)
      gload16(A + (size_t)(m0 + c * 16 + srow) * lda + kt + scol, (char*)As + c * 1024);
    for (int c = wave; c < BN / 16; c += NW)
      gload16(BT + (size_t)(n0 + c * 16 + srow) * K + kt + scol, (char*)Bs + c * 1024);
    __syncthreads();
    bf16x8 af[4], bfr[4];
#pragma unroll
    for (int i = 0; i < 4; i++)
      af[i] = *reinterpret_cast<const bf16x8*>(As + (wm + i * 16 + lr) * BK + lk * 8);
#pragma unroll
    for (int j = 0; j < 4; j++)
      bfr[j] = *reinterpret_cast<const bf16x8*>(Bs + (wn + j * 16 + lr) * BK + lk * 8);
    __builtin_amdgcn_s_setprio(1);
#pragma unroll
    for (int i = 0; i < 4; i++)
#pragma unroll
      for (int j = 0; j < 4; j++)
        acc[i][j] = __builtin_amdgcn_mfma_f32_16x16x32_bf16(af[i], bfr[j], acc[i][j], 0, 0, 0);
    __builtin_amdgcn_s_setprio(0);
    __syncthreads();
  }
#pragma unroll
  for (int i = 0; i < 4; i++)
#pragma unroll
    for (int j = 0; j < 4; j++) {
      int row = m0 + wm + i * 16 + lk * 4, col = n0 + wn + j * 16 + lr;
#pragma unroll
      for (int r = 0; r < 4; r++) {
        float v = acc[i][j][r];
        if constexpr (std::is_same<OutT, float>::value)
          C[(size_t)(row + r) * ldc + col] = v;
        else
          C[(size_t)(row + r) * ldc + col] = f2bf(v);
      }
    }
}

template <int BM, int BN, typename OutT>
__global__ __launch_bounds__(256)
void k_gemm_bt(const bf16* __restrict__ A, int lda, const bf16* __restrict__ BT,
               OutT* __restrict__ C, int ldc, int K) {
  gemm_body<BM, BN, OutT>(A, lda, BT, C, ldc, K, blockIdx.y * BM, blockIdx.x * BN);
}

// fused GEMM2+GEMM3: N = 4096 (kv) then 3072 (q3), both K=512, A = out1 col slices
__global__ __launch_bounds__(256)
void k_gemm23(const bf16* __restrict__ out1, const bf16* __restrict__ wt2,
              const bf16* __restrict__ wt3, bf16* __restrict__ kv, bf16* __restrict__ q3) {
  int n0g = blockIdx.x * 128, m0 = blockIdx.y * 128;
  const bf16* A; const bf16* BT; bf16* C; int ldc, n0;
  if (n0g < LDKV) { A = out1;       BT = wt2; C = kv; ldc = LDKV; n0 = n0g; }
  else            { A = out1 + 512; BT = wt3; C = q3; ldc = LDQ3; n0 = n0g - LDKV; }
  gemm_body<128, 128, bf16>(A, LDW1, BT, C, ldc, LAT, m0, n0);
}

// ---------------- rope on 8 contiguous elems (4 pairs) ----------------
__device__ __forceinline__ bf16x8 rope8(bf16x8 x, float4 c4, float4 s4) {
  bf16x8 o;
  float cp[4] = {c4.x, c4.y, c4.z, c4.w};
  float sp[4] = {s4.x, s4.y, s4.z, s4.w};
#pragma unroll
  for (int pe = 0; pe < 4; pe++) {
    float x0 = (float)x[2 * pe], x1 = (float)x[2 * pe + 1];
    o[2 * pe]     = (__bf16)(x0 * cp[pe] - x1 * sp[pe]);
    o[2 * pe + 1] = (__bf16)(x1 * cp[pe] + x0 * sp[pe]);
  }
  return o;
}

// ---------------- fused assemble: qbuf / kbuf (vectorized) / v-transpose ----------------
// zones: [0,6144) qbuf; [6144,12288) kbuf; [12288,20480) vt
__global__ void k_assemble(const bf16* __restrict__ q3, const bf16* __restrict__ kv,
                           const bf16* __restrict__ out1,
                           const float* __restrict__ cosT, const float* __restrict__ sinT,
                           bf16* __restrict__ qbuf, bf16* __restrict__ kbuf,
                           bf16* __restrict__ vt) {
  __shared__ bf16 tv[32][34];
  int blk = blockIdx.x;
  if (blk < 12288) {
    bool isQ = blk < 6144;
    int gid = (isQ ? blk : blk - 6144) * 256 + threadIdx.x;
    int rowIdx = gid / 24, pos = gid - rowIdx * 24;
    int d8 = pos * 8;
    int s = rowIdx & (SEQ - 1);
    int bhh = rowIdx >> 11;
    int hh = bhh & 15, b = bhh >> 4;
    size_t row = (size_t)b * SEQ + s;
    bf16x8 o;
    if (isQ) {
      if (d8 < HD) {
        o = *reinterpret_cast<const bf16x8*>(&q3[row * LDQ3 + hh * HD + d8]);
      } else {
        int dd8 = d8 - HD;
        bf16x8 x = *reinterpret_cast<const bf16x8*>(&q3[row * LDQ3 + HID + hh * RD + dd8]);
        float4 c4 = *reinterpret_cast<const float4*>(&cosT[s * 32 + (dd8 >> 1)]);
        float4 s4 = *reinterpret_cast<const float4*>(&sinT[s * 32 + (dd8 >> 1)]);
        o = rope8(x, c4, s4);
      }
      *reinterpret_cast<bf16x8*>(&qbuf[(size_t)gid * 8]) = o;
    } else {
      if (d8 < HD) {
        o = *reinterpret_cast<const bf16x8*>(&kv[row * LDKV + hh * HD + d8]);
      } else {
        int dd8 = d8 - HD;
        bf16x8 x = *reinterpret_cast<const bf16x8*>(&out1[row * LDW1 + 1024 + dd8]);
        float4 c4 = *reinterpret_cast<const float4*>(&cosT[s * 32 + (dd8 >> 1)]);
        float4 s4 = *reinterpret_cast<const float4*>(&sinT[s * 32 + (dd8 >> 1)]);
        o = rope8(x, c4, s4);
      }
      *reinterpret_cast<bf16x8*>(&kbuf[(size_t)gid * 8]) = o;
    }
    return;
  }
  // V transpose: kv[b*S+s][2048 + h*128+d] -> vt[bh][d][s]
  int local = blk - 12288;
  int dx = local & 3, sy = (local >> 2) & 63, bh = local >> 8;
  int b = bh >> 4, hh = bh & 15;
  int s0 = sy * 32, d0 = dx * 32;
  int c = threadIdx.x & 31, r0 = threadIdx.x >> 5;
#pragma unroll
  for (int i = 0; i < 32; i += 8)
    tv[r0 + i][c] = kv[((size_t)b * SEQ + s0 + r0 + i) * LDKV + HID + hh * HD + d0 + c];
  __syncthreads();
#pragma unroll
  for (int i = 0; i < 32; i += 8)
    vt[((size_t)bh * HD + d0 + r0 + i) * SEQ + s0 + c] = tv[c][r0 + i];
}

// ---------------- causal flash attention, paired Q-tiles (uniform load) ----------------
__global__ __launch_bounds__(256)
void k_attn(const bf16* __restrict__ Q, const bf16* __restrict__ Kb,
            const bf16* __restrict__ VT, bf16* __restrict__ Of) {
  constexpr int KBL = 64, NT = SEQ / 64;  // 32 KV tiles
  __shared__ alignas(16) bf16 Ks[KBL * DQK];
  __shared__ alignas(16) bf16 Vs[HD * KBL];
  __shared__ alignas(16) bf16 Ps[4 * 16 * KBL];
  // bijective XCD chunking: 16 pair-blocks sharing a bh land on one XCD
  const int nid = (blockIdx.x & 7) * 64 + (blockIdx.x >> 3);
  const int bh = nid >> 4, pid = nid & 15;
  const int qtA = pid, qtB = NT - 1 - pid;
  const int b = bh >> 4, hh = bh & 15;
  const int tid = threadIdx.x, wave = tid >> 6, lane = tid & 63;
  const int lr = lane & 15, lk = lane >> 4;
  const int rb = wave * 16 + lk * 4;  // row base within Q tile
  const float scale = 0.07216878364870323f;  // 1/sqrt(192)

  bf16x8 qf[2][6];
#pragma unroll
  for (int t = 0; t < 2; t++) {
    int q0 = (t ? qtB : qtA) * 64;
    const bf16* Qp = Q + ((size_t)bh * SEQ + q0 + wave * 16 + lr) * DQK;
#pragma unroll
    for (int c = 0; c < 6; c++)
      qf[t][c] = *reinterpret_cast<const bf16x8*>(Qp + c * 32 + lk * 8);
  }

  bf16* PsW = Ps + wave * (16 * KBL);
  f32x4 oacc[2][8] = {};
  float mrow[2][4], lrow[2][4];
#pragma unroll
  for (int t = 0; t < 2; t++)
#pragma unroll
    for (int r = 0; r < 4; r++) { mrow[t][r] = -INFINITY; lrow[t][r] = 0.f; }

  auto proc = [&](auto tc, bool maskit, int k0, int q0) {
    constexpr int t = decltype(tc)::value;
    f32x4 sc[4] = {};
    __builtin_amdgcn_s_setprio(1);
#pragma unroll
    for (int cb = 0; cb < 4; cb++) {
      const int krow = cb * 16 + lr;
#pragma unroll
      for (int c = 0; c < 6; c++) {
        int phys = (c * 4 + lk) ^ (krow & 7);
        bf16x8 kf = *reinterpret_cast<const bf16x8*>(Ks + krow * DQK + phys * 8);
        sc[cb] = __builtin_amdgcn_mfma_f32_16x16x32_bf16(qf[t][c], kf, sc[cb], 0, 0, 0);
      }
    }
    __builtin_amdgcn_s_setprio(0);
    float p[4][4], tm[4];
#pragma unroll
    for (int r = 0; r < 4; r++) tm[r] = -INFINITY;
#pragma unroll
    for (int cb = 0; cb < 4; cb++) {
      const int kcg = k0 + cb * 16 + lr;
#pragma unroll
      for (int r = 0; r < 4; r++) {
        float v = sc[cb][r] * scale;
        if (maskit && kcg > q0 + rb + r) v = -INFINITY;
        p[cb][r] = v;
        tm[r] = fmaxf(tm[r], v);
      }
    }
#pragma unroll
    for (int m = 1; m < 16; m <<= 1)
#pragma unroll
      for (int r = 0; r < 4; r++) tm[r] = fmaxf(tm[r], __shfl_xor(tm[r], m, 16));
    float rs[4];
#pragma unroll
    for (int r = 0; r < 4; r++) {
      float mo = mrow[t][r];
      float mn = fmaxf(mo, tm[r]);
      if (tm[r] > mo) {  // exact defer: skip rescale when multiplier would be 1.0
        float al = __expf(mo - mn);
        mrow[t][r] = mn;
        lrow[t][r] *= al;
#pragma unroll
        for (int ocb = 0; ocb < 8; ocb++) oacc[t][ocb][r] *= al;
      }
      float ssum = 0.f;
#pragma unroll
      for (int cb = 0; cb < 4; cb++) {
        float e = __expf(p[cb][r] - mn);
        p[cb][r] = e;
        ssum += e;
      }
      rs[r] = ssum;
    }
#pragma unroll
    for (int m = 1; m < 16; m <<= 1)
#pragma unroll
      for (int r = 0; r < 4; r++) rs[r] += __shfl_xor(rs[r], m, 16);
#pragma unroll
    for (int r = 0; r < 4; r++) lrow[t][r] += rs[r];
#pragma unroll
    for (int cb = 0; cb < 4; cb++)
#pragma unroll
      for (int r = 0; r < 4; r++) {
        int prow = lk * 4 + r;
        int pslot = (cb * 2 + (lr >> 3)) ^ (prow & 7);
        PsW[prow * KBL + pslot * 8 + (lr & 7)] = f2bf(p[cb][r]);
      }
    __builtin_amdgcn_s_setprio(1);
#pragma unroll
    for (int kk = 0; kk < 2; kk++) {
      int pphys = (kk * 4 + lk) ^ (lr & 7);
      bf16x8 pa = *reinterpret_cast<const bf16x8*>(PsW + lr * KBL + pphys * 8);
#pragma unroll
      for (int ocb = 0; ocb < 8; ocb++) {
        int vrow = ocb * 16 + lr;
        int vphys = (kk * 4 + lk) ^ (vrow & 7);
        bf16x8 vb = *reinterpret_cast<const bf16x8*>(Vs + vrow * KBL + vphys * 8);
        oacc[t][ocb] = __builtin_amdgcn_mfma_f32_16x16x32_bf16(pa, vb, oacc[t][ocb], 0, 0, 0);
      }
    }
    __builtin_amdgcn_s_setprio(0);
  };

  for (int kt = 0; kt <= qtB; kt++) {
    const int k0 = kt * KBL;
    const bf16* Kbase = Kb + ((size_t)bh * SEQ + k0) * DQK;
    const bf16* Vbase = VT + (size_t)bh * HD * SEQ + k0;
    for (int c = wave; c < 24; c += 4) {
      int S = c * 64 + lane;
      int row = S / 24;
      int scl = (S - row * 24) ^ (row & 7);
      gload16(Kbase + row * DQK + scl * 8, (char*)Ks + c * 1024);
    }
    for (int c = wave; c < 16; c += 4) {
      int S = c * 64 + lane;
      int row = S >> 3;
      int scl = (S & 7) ^ (row & 7);
      gload16(Vbase + (size_t)row * SEQ + scl * 8, (char*)Vs + c * 1024);
    }
    __syncthreads();
    proc(std::integral_constant<int, 1>{}, kt == qtB, k0, qtB * 64);
    if (kt <= qtA) proc(std::integral_constant<int, 0>{}, kt == qtA, k0, qtA * 64);
    __syncthreads();
  }

#pragma unroll
  for (int t = 0; t < 2; t++) {
    int q0 = (t ? qtB : qtA) * 64;
#pragma unroll
    for (int ocb = 0; ocb < 8; ocb++)
#pragma unroll
      for (int r = 0; r < 4; r++) {
        int qr = q0 + rb + r;
        float v = oacc[t][ocb][r] / lrow[t][r];
        Of[((size_t)b * SEQ + qr) * HID + hh * HD + ocb * 16 + lr] = f2bf(v);
      }
  }
}

// ---------------- host launch ----------------
extern "C" void kernel_launch(void* const* d_in, const int* in_sizes, int n_in,
                              void* d_out, int out_size, void* d_ws, size_t ws_size,
                              hipStream_t stream) {
  const float* h    = (const float*)d_in[0];
  const float* Wdkv = (const float*)d_in[1];
  const float* Wuk  = (const float*)d_in[2];
  const float* Wkr  = (const float*)d_in[3];
  const float* Wuv  = (const float*)d_in[4];
  const float* Wdq  = (const float*)d_in[5];
  const float* Wuq  = (const float*)d_in[6];
  const float* Wqr  = (const float*)d_in[7];
  const float* Wo   = (const float*)d_in[8];
  float* out = (float*)d_out;

  char* w = (char*)d_ws;
  auto alloc = [&](size_t elems) {
    bf16* p = (bf16*)w;
    w += (elems * sizeof(bf16) + 255) & ~(size_t)255;
    return p;
  };
  bf16* hb   = alloc((size_t)MR * HID);
  bf16* wt1  = alloc((size_t)LDW1 * HID);
  bf16* wt2  = alloc((size_t)LDKV * LAT);
  bf16* wt3  = alloc((size_t)LDQ3 * LAT);
  bf16* woT  = alloc((size_t)HID * HID);
  bf16* out1 = alloc((size_t)MR * LDW1);
  bf16* kv   = alloc((size_t)MR * LDKV);
  bf16* q3   = alloc((size_t)MR * LDQ3);
  bf16* qbuf = alloc((size_t)BB * NHEAD * SEQ * DQK);
  bf16* kbuf = alloc((size_t)BB * NHEAD * SEQ * DQK);
  bf16* vt   = alloc((size_t)BB * NHEAD * HD * SEQ);
  bf16* oflat= alloc((size_t)MR * HID);
  float* cosT = (float*)alloc((size_t)SEQ * 32 * 2);
  float* sinT = (float*)alloc((size_t)SEQ * 32 * 2);

  // 1) all prep (weights, rope, h->bf16)
  k_prep<<<18304, 256, 0, stream>>>(h, Wdkv, Wdq, Wkr, Wuk, Wuv, Wuq, Wqr, Wo,
                                    hb, wt1, wt2, wt3, woT, cosT, sinT);
  // 2) fused proj-1: out1 = hb @ [Wdkv|Wdq|Wkr]
  k_gemm_bt<128, 128, bf16><<<dim3(LDW1 / 128, MR / 128), 256, 0, stream>>>(hb, HID, wt1, out1, LDW1, HID);
  // 3) fused proj-2/3: kv = ckv @ [Wuk|Wuv]; q3 = cq @ [Wuq|Wqr]
  k_gemm23<<<dim3((LDKV + LDQ3) / 128, MR / 128), 256, 0, stream>>>(out1, wt2, wt3, kv, q3);
  // 4) assemble q/k (rope) + v transpose
  k_assemble<<<20480, 256, 0, stream>>>(q3, kv, out1, cosT, sinT, qbuf, kbuf, vt);
  // 5) attention (paired causal tiles, uniform load)
  k_attn<<<512, 256, 0, stream>>>(qbuf, kbuf, vt, oflat);
  // 6) output projection
  k_gemm_bt<128, 128, float><<<dim3(HID / 128, MR / 128), 256, 0, stream>>>(oflat, HID, woT, out, HID, HID);
}

// Round 5
// 476.727 us; speedup vs baseline: 1.0516x; 1.0516x over previous
//
#include <hip/hip_runtime.h>
#include <hip/hip_bf16.h>
#include <type_traits>
#include <cstdint>

typedef __bf16 bf16x8 __attribute__((ext_vector_type(8)));
typedef float f32x4 __attribute__((ext_vector_type(4)));
typedef __hip_bfloat16 bf16;

static constexpr int BB = 2, SEQ = 2048, HID = 2048, LAT = 512, NHEAD = 16;
static constexpr int HD = 128, RD = 64, DQK = 192;
static constexpr int MR = BB * SEQ;  // 4096 rows
static constexpr int LDW1 = 1152;    // fused proj-1 output cols
static constexpr int LDKV = 4096;    // [k_C | v]
static constexpr int LDQ3 = 3072;    // [q_C | q_R]

__device__ __forceinline__ float bf2f(bf16 x) { return __bfloat162float(x); }
__device__ __forceinline__ bf16 f2bf(float x) { return __float2bfloat16(x); }

__device__ __forceinline__ void gload16(const void* g, void* l) {
  __builtin_amdgcn_global_load_lds(
      (__attribute__((address_space(1))) void*)(uintptr_t)g,
      (__attribute__((address_space(3))) void*)(uint32_t)(uintptr_t)l,
      16, 0, 0);
}

// ---------------- fused prep: weight transposes + rope tables + h convert ----------------
__global__ void k_prep(const float* __restrict__ h,
                       const float* __restrict__ Wdkv, const float* __restrict__ Wdq,
                       const float* __restrict__ Wkr, const float* __restrict__ Wuk,
                       const float* __restrict__ Wuv, const float* __restrict__ Wuq,
                       const float* __restrict__ Wqr, const float* __restrict__ Wo,
                       bf16* __restrict__ hb, bf16* __restrict__ wt1, bf16* __restrict__ wt2,
                       bf16* __restrict__ wt3, bf16* __restrict__ woT,
                       float* __restrict__ cosT, float* __restrict__ sinT) {
  __shared__ float tbuf[32][33];
  int blk = blockIdx.x;
  if (blk >= 10112) {  // h fp32->bf16, float4 per thread
    int i = (blk - 10112) * 256 + threadIdx.x;
    float4 v = reinterpret_cast<const float4*>(h)[i];
    bf16* o = hb + (size_t)i * 4;
    o[0] = f2bf(v.x); o[1] = f2bf(v.y); o[2] = f2bf(v.z); o[3] = f2bf(v.w);
    return;
  }
  if (blk >= 9856) {  // rope tables
    int idx = (blk - 9856) * 256 + threadIdx.x;
    int s = idx >> 5, j = idx & 31;
    float freq = powf(10000.0f, -(float)(2 * j) / 64.0f);
    float a = (float)s * freq;
    cosT[idx] = cosf(a);
    sinT[idx] = sinf(a);
    return;
  }
  const float* src; bf16* dst; int K, N, local;
  if (blk < 1024)      { src = Wdkv; dst = wt1;                      K = 2048; N = 512;  local = blk; }
  else if (blk < 2048) { src = Wdq;  dst = wt1 + (size_t)512 * 2048; K = 2048; N = 512;  local = blk - 1024; }
  else if (blk < 2176) { src = Wkr;  dst = wt1 + (size_t)1024 * 2048;K = 2048; N = 64;   local = blk - 2048; }
  else if (blk < 3200) { src = Wuk;  dst = wt2;                      K = 512;  N = 2048; local = blk - 2176; }
  else if (blk < 4224) { src = Wuv;  dst = wt2 + (size_t)2048 * 512; K = 512;  N = 2048; local = blk - 3200; }
  else if (blk < 5248) { src = Wuq;  dst = wt3;                      K = 512;  N = 2048; local = blk - 4224; }
  else if (blk < 5760) { src = Wqr;  dst = wt3 + (size_t)2048 * 512; K = 512;  N = 1024; local = blk - 5248; }
  else                 { src = Wo;   dst = woT;                      K = 2048; N = 2048; local = blk - 5760; }
  int tilesX = N >> 5;
  int tx = local % tilesX, ty = local / tilesX;
  int k0 = ty * 32, n0 = tx * 32;
  int c = threadIdx.x & 31, r0 = threadIdx.x >> 5;
#pragma unroll
  for (int i = 0; i < 32; i += 8) tbuf[r0 + i][c] = src[(size_t)(k0 + r0 + i) * N + n0 + c];
  __syncthreads();
#pragma unroll
  for (int i = 0; i < 32; i += 8)
    dst[(size_t)(n0 + r0 + i) * K + k0 + c] = f2bf(tbuf[c][r0 + i]);
}

// ---------------- GEMM body (m97 structure) ----------------
template <int BM, int BN, typename OutT>
__device__ __forceinline__ void gemm_body(const bf16* __restrict__ A, int lda,
                                          const bf16* __restrict__ BT,
                                          OutT* __restrict__ C, int ldc, int K,
                                          int m0, int n0) {
  constexpr int BK = 32;
  constexpr int WN = BN / 64, NW = (BM / 64) * WN;
  __shared__ alignas(16) bf16 As[BM * BK];
  __shared__ alignas(16) bf16 Bs[BN * BK];
  const int tid = threadIdx.x, wave = tid >> 6, lane = tid & 63;
  const int lr = lane & 15, lk = lane >> 4;
  const int wm = (wave / WN) * 64, wn = (wave % WN) * 64;
  const int srow = lane >> 2;
  const int scol = (lane & 3) * 8;
  f32x4 acc[4][4] = {};
  for (int kt = 0; kt < K; kt += BK) {
    for (int c = wave; c < BM / 16; c += NW)
      gload16(A + (size_t)(m0 + c * 16 + srow) * lda + kt + scol, (char*)As + c * 1024);
    for (int c = wave; c < BN / 16; c += NW)
      gload16(BT + (size_t)(n0 + c * 16 + srow) * K + kt + scol, (char*)Bs + c * 1024);
    __syncthreads();
    bf16x8 af[4], bfr[4];
#pragma unroll
    for (int i = 0; i < 4; i++)
      af[i] = *reinterpret_cast<const bf16x8*>(As + (wm + i * 16 + lr) * BK + lk * 8);
#pragma unroll
    for (int j = 0; j < 4; j++)
      bfr[j] = *reinterpret_cast<const bf16x8*>(Bs + (wn + j * 16 + lr) * BK + lk * 8);
    __builtin_amdgcn_s_setprio(1);
#pragma unroll
    for (int i = 0; i < 4; i++)
#pragma unroll
      for (int j = 0; j < 4; j++)
        acc[i][j] = __builtin_amdgcn_mfma_f32_16x16x32_bf16(af[i], bfr[j], acc[i][j], 0, 0, 0);
    __builtin_amdgcn_s_setprio(0);
    __syncthreads();
  }
#pragma unroll
  for (int i = 0; i < 4; i++)
#pragma unroll
    for (int j = 0; j < 4; j++) {
      int row = m0 + wm + i * 16 + lk * 4, col = n0 + wn + j * 16 + lr;
#pragma unroll
      for (int r = 0; r < 4; r++) {
        float v = acc[i][j][r];
        if constexpr (std::is_same<OutT, float>::value)
          C[(size_t)(row + r) * ldc + col] = v;
        else
          C[(size_t)(row + r) * ldc + col] = f2bf(v);
      }
    }
}

template <int BM, int BN, typename OutT>
__global__ __launch_bounds__(256)
void k_gemm_bt(const bf16* __restrict__ A, int lda, const bf16* __restrict__ BT,
               OutT* __restrict__ C, int ldc, int K) {
  gemm_body<BM, BN, OutT>(A, lda, BT, C, ldc, K, blockIdx.y * BM, blockIdx.x * BN);
}

// fused GEMM2+GEMM3
__global__ __launch_bounds__(256)
void k_gemm23(const bf16* __restrict__ out1, const bf16* __restrict__ wt2,
              const bf16* __restrict__ wt3, bf16* __restrict__ kv, bf16* __restrict__ q3) {
  int n0g = blockIdx.x * 128, m0 = blockIdx.y * 128;
  const bf16* A; const bf16* BT; bf16* C; int ldc, n0;
  if (n0g < LDKV) { A = out1;       BT = wt2; C = kv; ldc = LDKV; n0 = n0g; }
  else            { A = out1 + 512; BT = wt3; C = q3; ldc = LDQ3; n0 = n0g - LDKV; }
  gemm_body<128, 128, bf16>(A, LDW1, BT, C, ldc, LAT, m0, n0);
}

// ---------------- rope on 8 contiguous elems (4 pairs) ----------------
__device__ __forceinline__ bf16x8 rope8(bf16x8 x, float4 c4, float4 s4) {
  bf16x8 o;
  float cp[4] = {c4.x, c4.y, c4.z, c4.w};
  float sp[4] = {s4.x, s4.y, s4.z, s4.w};
#pragma unroll
  for (int pe = 0; pe < 4; pe++) {
    float x0 = (float)x[2 * pe], x1 = (float)x[2 * pe + 1];
    o[2 * pe]     = (__bf16)(x0 * cp[pe] - x1 * sp[pe]);
    o[2 * pe + 1] = (__bf16)(x1 * cp[pe] + x0 * sp[pe]);
  }
  return o;
}

// ---------------- fused assemble: qbuf / kbuf / v-transpose ----------------
__global__ void k_assemble(const bf16* __restrict__ q3, const bf16* __restrict__ kv,
                           const bf16* __restrict__ out1,
                           const float* __restrict__ cosT, const float* __restrict__ sinT,
                           bf16* __restrict__ qbuf, bf16* __restrict__ kbuf,
                           bf16* __restrict__ vt) {
  __shared__ bf16 tv[32][34];
  int blk = blockIdx.x;
  if (blk < 12288) {
    bool isQ = blk < 6144;
    int gid = (isQ ? blk : blk - 6144) * 256 + threadIdx.x;
    int rowIdx = gid / 24, pos = gid - rowIdx * 24;
    int d8 = pos * 8;
    int s = rowIdx & (SEQ - 1);
    int bhh = rowIdx >> 11;
    int hh = bhh & 15, b = bhh >> 4;
    size_t row = (size_t)b * SEQ + s;
    bf16x8 o;
    if (isQ) {
      if (d8 < HD) {
        o = *reinterpret_cast<const bf16x8*>(&q3[row * LDQ3 + hh * HD + d8]);
      } else {
        int dd8 = d8 - HD;
        bf16x8 x = *reinterpret_cast<const bf16x8*>(&q3[row * LDQ3 + HID + hh * RD + dd8]);
        float4 c4 = *reinterpret_cast<const float4*>(&cosT[s * 32 + (dd8 >> 1)]);
        float4 s4 = *reinterpret_cast<const float4*>(&sinT[s * 32 + (dd8 >> 1)]);
        o = rope8(x, c4, s4);
      }
      *reinterpret_cast<bf16x8*>(&qbuf[(size_t)gid * 8]) = o;
    } else {
      if (d8 < HD) {
        o = *reinterpret_cast<const bf16x8*>(&kv[row * LDKV + hh * HD + d8]);
      } else {
        int dd8 = d8 - HD;
        bf16x8 x = *reinterpret_cast<const bf16x8*>(&out1[row * LDW1 + 1024 + dd8]);
        float4 c4 = *reinterpret_cast<const float4*>(&cosT[s * 32 + (dd8 >> 1)]);
        float4 s4 = *reinterpret_cast<const float4*>(&sinT[s * 32 + (dd8 >> 1)]);
        o = rope8(x, c4, s4);
      }
      *reinterpret_cast<bf16x8*>(&kbuf[(size_t)gid * 8]) = o;
    }
    return;
  }
  int local = blk - 12288;
  int dx = local & 3, sy = (local >> 2) & 63, bh = local >> 8;
  int b = bh >> 4, hh = bh & 15;
  int s0 = sy * 32, d0 = dx * 32;
  int c = threadIdx.x & 31, r0 = threadIdx.x >> 5;
#pragma unroll
  for (int i = 0; i < 32; i += 8)
    tv[r0 + i][c] = kv[((size_t)b * SEQ + s0 + r0 + i) * LDKV + HID + hh * HD + d0 + c];
  __syncthreads();
#pragma unroll
  for (int i = 0; i < 32; i += 8)
    vt[((size_t)bh * HD + d0 + r0 + i) * SEQ + s0 + c] = tv[c][r0 + i];
}

// ---------------- causal flash attention: longest-first, KBL=32, double-buffered,
// ---------------- one barrier per KV tile (T3 minimum 2-phase) ----------------
__global__ __launch_bounds__(256)
void k_attn(const bf16* __restrict__ Q, const bf16* __restrict__ Kb,
            const bf16* __restrict__ VT, bf16* __restrict__ Of) {
  constexpr int QB = 64, KBL = 32;
  // K: 32x192 bf16, XOR(row&7) on 16B slots. V: 128 rows x 80B (64B data + 16B pad),
  // pad stride => banks spread, no swizzle. P: per-wave 16x32, XOR(row&3) on slots.
  __shared__ alignas(16) bf16 Ks[2][KBL * DQK];   // 2 x 12 KB
  __shared__ alignas(16) bf16 Vs[2][HD * 40];     // 2 x 10 KB
  __shared__ alignas(16) bf16 Ps[4][16 * KBL];    // 4 KB
  const int qt = (SEQ / QB - 1) - (blockIdx.x >> 5);  // longest-first
  const int bh = blockIdx.x & 31;
  const int b = bh >> 4, hh = bh & 15;
  const int tid = threadIdx.x, wave = tid >> 6, lane = tid & 63;
  const int lr = lane & 15, lk = lane >> 4;
  const int q0 = qt * QB;
  const int rb = wave * 16 + lk * 4;
  const float scale = 0.07216878364870323f;  // 1/sqrt(192)

  const bf16* Qp = Q + ((size_t)bh * SEQ + q0 + wave * 16 + lr) * DQK;
  bf16x8 qf[6];
#pragma unroll
  for (int c = 0; c < 6; c++)
    qf[c] = *reinterpret_cast<const bf16x8*>(Qp + c * 32 + lk * 8);

  bf16* PsW = Ps[wave];
  const bf16* Kbh = Kb + (size_t)bh * SEQ * DQK;
  const bf16* Vbh = VT + (size_t)bh * HD * SEQ;

  f32x4 oacc[8] = {};
  float mrow[4], lrow[4];
#pragma unroll
  for (int r = 0; r < 4; r++) { mrow[r] = -INFINITY; lrow[r] = 0.f; }

  auto stage = [&](int nb, int kt) {
    const bf16* Kbase = Kbh + (size_t)kt * KBL * DQK;
    const bf16* Vbase = Vbh + kt * KBL;
    // K: 12 KB = 12 wave-issues; pre-swizzled source, linear dest
    for (int c = wave; c < 12; c += 4) {
      int S = c * 64 + lane;
      int row = S / 24;
      int scl = (S - row * 24) ^ (row & 7);
      gload16(Kbase + row * DQK + scl * 8, (char*)Ks[nb] + c * 1024);
    }
    // V: 10 KB = 10 wave-issues; 5 x 16B slots per 80B row (last slot = pad)
    for (int c = wave; c < 10; c += 4) {
      int S = c * 64 + lane;
      int row = S / 5;
      int sl = S - row * 5;
      gload16(Vbase + (size_t)row * SEQ + sl * 8, (char*)Vs[nb] + c * 1024);
    }
  };

  const int ktmax = 2 * qt + 1;
  stage(0, 0);
  __syncthreads();

  for (int kt = 0; kt <= ktmax; kt++) {
    const int buf = kt & 1;
    if (kt < ktmax) stage(buf ^ 1, kt + 1);
    const int k0 = kt * KBL;
    const bf16* Kt = Ks[buf];

    f32x4 sc[2] = {};
    __builtin_amdgcn_s_setprio(1);
#pragma unroll
    for (int cb = 0; cb < 2; cb++) {
      const int krow = cb * 16 + lr;
#pragma unroll
      for (int c = 0; c < 6; c++) {
        int phys = (c * 4 + lk) ^ (krow & 7);
        bf16x8 kf = *reinterpret_cast<const bf16x8*>(Kt + krow * DQK + phys * 8);
        sc[cb] = __builtin_amdgcn_mfma_f32_16x16x32_bf16(qf[c], kf, sc[cb], 0, 0, 0);
      }
    }
    __builtin_amdgcn_s_setprio(0);

    const bool maskit = (kt >= 2 * qt);
    float p[2][4], tm[4];
#pragma unroll
    for (int r = 0; r < 4; r++) tm[r] = -INFINITY;
#pragma unroll
    for (int cb = 0; cb < 2; cb++) {
      const int kcg = k0 + cb * 16 + lr;
#pragma unroll
      for (int r = 0; r < 4; r++) {
        float v = sc[cb][r] * scale;
        if (maskit && kcg > q0 + rb + r) v = -INFINITY;
        p[cb][r] = v;
        tm[r] = fmaxf(tm[r], v);
      }
    }
#pragma unroll
    for (int m = 1; m < 16; m <<= 1)
#pragma unroll
      for (int r = 0; r < 4; r++) tm[r] = fmaxf(tm[r], __shfl_xor(tm[r], m, 16));

    float rs[4];
#pragma unroll
    for (int r = 0; r < 4; r++) {
      float mo = mrow[r];
      float mn = fmaxf(mo, tm[r]);
      if (tm[r] > mo) {  // exact defer: multiplier==1.0 -> skip rescale
        float al = __expf(mo - mn);
        mrow[r] = mn;
        lrow[r] *= al;
#pragma unroll
        for (int ocb = 0; ocb < 8; ocb++) oacc[ocb][r] *= al;
      }
      float ssum = 0.f;
#pragma unroll
      for (int cb = 0; cb < 2; cb++) {
        float e = __expf(p[cb][r] - mn);
        p[cb][r] = e;
        ssum += e;
      }
      rs[r] = ssum;
    }
#pragma unroll
    for (int m = 1; m < 16; m <<= 1)
#pragma unroll
      for (int r = 0; r < 4; r++) rs[r] += __shfl_xor(rs[r], m, 16);
#pragma unroll
    for (int r = 0; r < 4; r++) lrow[r] += rs[r];

    // P -> LDS (wave-private): row=lk*4+r, col=cb*16+lr, phys slot = slot ^ (row&3)
#pragma unroll
    for (int cb = 0; cb < 2; cb++)
#pragma unroll
      for (int r = 0; r < 4; r++) {
        int prow = lk * 4 + r;
        int pslot = (cb * 2 + (lr >> 3)) ^ r;
        PsW[prow * KBL + pslot * 8 + (lr & 7)] = f2bf(p[cb][r]);
      }

    __builtin_amdgcn_s_setprio(1);
    {
      int pphys = lk ^ (lr & 3);
      bf16x8 pa = *reinterpret_cast<const bf16x8*>(PsW + lr * KBL + pphys * 8);
#pragma unroll
      for (int ocb = 0; ocb < 8; ocb++) {
        int vrow = ocb * 16 + lr;
        bf16x8 vb = *reinterpret_cast<const bf16x8*>((const char*)Vs[buf] + vrow * 80 + lk * 16);
        oacc[ocb] = __builtin_amdgcn_mfma_f32_16x16x32_bf16(pa, vb, oacc[ocb], 0, 0, 0);
      }
    }
    __builtin_amdgcn_s_setprio(0);
    __syncthreads();  // drains next-tile loads (overlapped with compute) + aligns waves
  }

#pragma unroll
  for (int ocb = 0; ocb < 8; ocb++)
#pragma unroll
    for (int r = 0; r < 4; r++) {
      int qr = q0 + rb + r;
      float v = oacc[ocb][r] / lrow[r];
      Of[((size_t)b * SEQ + qr) * HID + hh * HD + ocb * 16 + lr] = f2bf(v);
    }
}

// ---------------- host launch ----------------
extern "C" void kernel_launch(void* const* d_in, const int* in_sizes, int n_in,
                              void* d_out, int out_size, void* d_ws, size_t ws_size,
                              hipStream_t stream) {
  const float* h    = (const float*)d_in[0];
  const float* Wdkv = (const float*)d_in[1];
  const float* Wuk  = (const float*)d_in[2];
  const float* Wkr  = (const float*)d_in[3];
  const float* Wuv  = (const float*)d_in[4];
  const float* Wdq  = (const float*)d_in[5];
  const float* Wuq  = (const float*)d_in[6];
  const float* Wqr  = (const float*)d_in[7];
  const float* Wo   = (const float*)d_in[8];
  float* out = (float*)d_out;

  char* w = (char*)d_ws;
  auto alloc = [&](size_t elems) {
    bf16* p = (bf16*)w;
    w += (elems * sizeof(bf16) + 255) & ~(size_t)255;
    return p;
  };
  bf16* hb   = alloc((size_t)MR * HID);
  bf16* wt1  = alloc((size_t)LDW1 * HID);
  bf16* wt2  = alloc((size_t)LDKV * LAT);
  bf16* wt3  = alloc((size_t)LDQ3 * LAT);
  bf16* woT  = alloc((size_t)HID * HID);
  bf16* out1 = alloc((size_t)MR * LDW1);
  bf16* kv   = alloc((size_t)MR * LDKV);
  bf16* q3   = alloc((size_t)MR * LDQ3);
  bf16* qbuf = alloc((size_t)BB * NHEAD * SEQ * DQK);
  bf16* kbuf = alloc((size_t)BB * NHEAD * SEQ * DQK);
  bf16* vt   = alloc((size_t)BB * NHEAD * HD * SEQ);
  bf16* oflat= alloc((size_t)MR * HID);
  float* cosT = (float*)alloc((size_t)SEQ * 32 * 2);
  float* sinT = (float*)alloc((size_t)SEQ * 32 * 2);

  // 1) all prep (weights, rope, h->bf16)
  k_prep<<<18304, 256, 0, stream>>>(h, Wdkv, Wdq, Wkr, Wuk, Wuv, Wuq, Wqr, Wo,
                                    hb, wt1, wt2, wt3, woT, cosT, sinT);
  // 2) fused proj-1: out1 = hb @ [Wdkv|Wdq|Wkr]
  k_gemm_bt<128, 128, bf16><<<dim3(LDW1 / 128, MR / 128), 256, 0, stream>>>(hb, HID, wt1, out1, LDW1, HID);
  // 3) fused proj-2/3: kv = ckv @ [Wuk|Wuv]; q3 = cq @ [Wuq|Wqr]
  k_gemm23<<<dim3((LDKV + LDQ3) / 128, MR / 128), 256, 0, stream>>>(out1, wt2, wt3, kv, q3);
  // 4) assemble q/k (rope) + v transpose
  k_assemble<<<20480, 256, 0, stream>>>(q3, kv, out1, cosT, sinT, qbuf, kbuf, vt);
  // 5) attention (longest-first, double-buffered KV pipeline)
  k_attn<<<(SEQ / 64) * 32, 256, 0, stream>>>(qbuf, kbuf, vt, oflat);
  // 6) output projection
  k_gemm_bt<128, 128, float><<<dim3(HID / 128, MR / 128), 256, 0, stream>>>(oflat, HID, woT, out, HID, HID);
}

// Round 7
// 423.546 us; speedup vs baseline: 1.1837x; 1.1256x over previous
//
#include <hip/hip_runtime.h>
#include <hip/hip_bf16.h>
#include <type_traits>
#include <cstdint>

typedef __bf16 bf16x8 __attribute__((ext_vector_type(8)));
typedef float f32x4 __attribute__((ext_vector_type(4)));
typedef __hip_bfloat16 bf16;

static constexpr int BB = 2, SEQ = 2048, HID = 2048, LAT = 512, NHEAD = 16;
static constexpr int HD = 128, RD = 64, DQK = 192;
static constexpr int MR = BB * SEQ;  // 4096 rows
static constexpr int LDW1 = 1152;    // fused proj-1 output cols
static constexpr int LDKV = 4096;    // [k_C | v]
static constexpr int LDQ3 = 3072;    // [q_C | q_R]
// scale(1/sqrt(192)) * log2(e) folded into Q so softmax runs in exp2 domain
static constexpr float QSC = 0.10411754f;

__device__ __forceinline__ float bf2f(bf16 x) { return __bfloat162float(x); }
__device__ __forceinline__ bf16 f2bf(float x) { return __float2bfloat16(x); }

__device__ __forceinline__ void gload16(const void* g, void* l) {
  __builtin_amdgcn_global_load_lds(
      (__attribute__((address_space(1))) void*)(uintptr_t)g,
      (__attribute__((address_space(3))) void*)(uint32_t)(uintptr_t)l,
      16, 0, 0);
}

// ---------------- fused prep: weight transposes + rope tables + h convert ----------------
__global__ void k_prep(const float* __restrict__ h,
                       const float* __restrict__ Wdkv, const float* __restrict__ Wdq,
                       const float* __restrict__ Wkr, const float* __restrict__ Wuk,
                       const float* __restrict__ Wuv, const float* __restrict__ Wuq,
                       const float* __restrict__ Wqr, const float* __restrict__ Wo,
                       bf16* __restrict__ hb, bf16* __restrict__ wt1, bf16* __restrict__ wt2,
                       bf16* __restrict__ wt3, bf16* __restrict__ woT,
                       float* __restrict__ cosT, float* __restrict__ sinT) {
  __shared__ float tbuf[32][33];
  int blk = blockIdx.x;
  if (blk >= 10112) {  // h fp32->bf16, float4 per thread
    int i = (blk - 10112) * 256 + threadIdx.x;
    float4 v = reinterpret_cast<const float4*>(h)[i];
    bf16* o = hb + (size_t)i * 4;
    o[0] = f2bf(v.x); o[1] = f2bf(v.y); o[2] = f2bf(v.z); o[3] = f2bf(v.w);
    return;
  }
  if (blk >= 9856) {  // rope tables
    int idx = (blk - 9856) * 256 + threadIdx.x;
    int s = idx >> 5, j = idx & 31;
    float freq = powf(10000.0f, -(float)(2 * j) / 64.0f);
    float a = (float)s * freq;
    cosT[idx] = cosf(a);
    sinT[idx] = sinf(a);
    return;
  }
  const float* src; bf16* dst; int K, N, local;
  if (blk < 1024)      { src = Wdkv; dst = wt1;                      K = 2048; N = 512;  local = blk; }
  else if (blk < 2048) { src = Wdq;  dst = wt1 + (size_t)512 * 2048; K = 2048; N = 512;  local = blk - 1024; }
  else if (blk < 2176) { src = Wkr;  dst = wt1 + (size_t)1024 * 2048;K = 2048; N = 64;   local = blk - 2048; }
  else if (blk < 3200) { src = Wuk;  dst = wt2;                      K = 512;  N = 2048; local = blk - 2176; }
  else if (blk < 4224) { src = Wuv;  dst = wt2 + (size_t)2048 * 512; K = 512;  N = 2048; local = blk - 3200; }
  else if (blk < 5248) { src = Wuq;  dst = wt3;                      K = 512;  N = 2048; local = blk - 4224; }
  else if (blk < 5760) { src = Wqr;  dst = wt3 + (size_t)2048 * 512; K = 512;  N = 1024; local = blk - 5248; }
  else                 { src = Wo;   dst = woT;                      K = 2048; N = 2048; local = blk - 5760; }
  int tilesX = N >> 5;
  int tx = local % tilesX, ty = local / tilesX;
  int k0 = ty * 32, n0 = tx * 32;
  int c = threadIdx.x & 31, r0 = threadIdx.x >> 5;
#pragma unroll
  for (int i = 0; i < 32; i += 8) tbuf[r0 + i][c] = src[(size_t)(k0 + r0 + i) * N + n0 + c];
  __syncthreads();
#pragma unroll
  for (int i = 0; i < 32; i += 8)
    dst[(size_t)(n0 + r0 + i) * K + k0 + c] = f2bf(tbuf[c][r0 + i]);
}

// ---------------- GEMM body (m97 structure) ----------------
template <int BM, int BN, typename OutT>
__device__ __forceinline__ void gemm_body(const bf16* __restrict__ A, int lda,
                                          const bf16* __restrict__ BT,
                                          OutT* __restrict__ C, int ldc, int K,
                                          int m0, int n0) {
  constexpr int BK = 32;
  constexpr int WN = BN / 64, NW = (BM / 64) * WN;
  __shared__ alignas(16) bf16 As[BM * BK];
  __shared__ alignas(16) bf16 Bs[BN * BK];
  const int tid = threadIdx.x, wave = tid >> 6, lane = tid & 63;
  const int lr = lane & 15, lk = lane >> 4;
  const int wm = (wave / WN) * 64, wn = (wave % WN) * 64;
  const int srow = lane >> 2;
  const int scol = (lane & 3) * 8;
  f32x4 acc[4][4] = {};
  for (int kt = 0; kt < K; kt += BK) {
    for (int c = wave; c < BM / 16; c += NW)
      gload16(A + (size_t)(m0 + c * 16 + srow) * lda + kt + scol, (char*)As + c * 1024);
    for (int c = wave; c < BN / 16; c += NW)
      gload16(BT + (size_t)(n0 + c * 16 + srow) * K + kt + scol, (char*)Bs + c * 1024);
    __syncthreads();
    bf16x8 af[4], bfr[4];
#pragma unroll
    for (int i = 0; i < 4; i++)
      af[i] = *reinterpret_cast<const bf16x8*>(As + (wm + i * 16 + lr) * BK + lk * 8);
#pragma unroll
    for (int j = 0; j < 4; j++)
      bfr[j] = *reinterpret_cast<const bf16x8*>(Bs + (wn + j * 16 + lr) * BK + lk * 8);
    __builtin_amdgcn_s_setprio(1);
#pragma unroll
    for (int i = 0; i < 4; i++)
#pragma unroll
      for (int j = 0; j < 4; j++)
        acc[i][j] = __builtin_amdgcn_mfma_f32_16x16x32_bf16(af[i], bfr[j], acc[i][j], 0, 0, 0);
    __builtin_amdgcn_s_setprio(0);
    __syncthreads();
  }
#pragma unroll
  for (int i = 0; i < 4; i++)
#pragma unroll
    for (int j = 0; j < 4; j++) {
      int row = m0 + wm + i * 16 + lk * 4, col = n0 + wn + j * 16 + lr;
#pragma unroll
      for (int r = 0; r < 4; r++) {
        float v = acc[i][j][r];
        if constexpr (std::is_same<OutT, float>::value)
          C[(size_t)(row + r) * ldc + col] = v;
        else
          C[(size_t)(row + r) * ldc + col] = f2bf(v);
      }
    }
}

template <int BM, int BN, typename OutT>
__global__ __launch_bounds__(256)
void k_gemm_bt(const bf16* __restrict__ A, int lda, const bf16* __restrict__ BT,
               OutT* __restrict__ C, int ldc, int K) {
  gemm_body<BM, BN, OutT>(A, lda, BT, C, ldc, K, blockIdx.y * BM, blockIdx.x * BN);
}

// fused GEMM2+GEMM3
__global__ __launch_bounds__(256)
void k_gemm23(const bf16* __restrict__ out1, const bf16* __restrict__ wt2,
              const bf16* __restrict__ wt3, bf16* __restrict__ kv, bf16* __restrict__ q3) {
  int n0g = blockIdx.x * 128, m0 = blockIdx.y * 128;
  const bf16* A; const bf16* BT; bf16* C; int ldc, n0;
  if (n0g < LDKV) { A = out1;       BT = wt2; C = kv; ldc = LDKV; n0 = n0g; }
  else            { A = out1 + 512; BT = wt3; C = q3; ldc = LDQ3; n0 = n0g - LDKV; }
  gemm_body<128, 128, bf16>(A, LDW1, BT, C, ldc, LAT, m0, n0);
}

// ---------------- rope on 8 contiguous elems (4 pairs), post-scale before rounding ----------------
__device__ __forceinline__ bf16x8 rope8(bf16x8 x, float4 c4, float4 s4, float postscale) {
  bf16x8 o;
  float cp[4] = {c4.x, c4.y, c4.z, c4.w};
  float sp[4] = {s4.x, s4.y, s4.z, s4.w};
#pragma unroll
  for (int pe = 0; pe < 4; pe++) {
    float x0 = (float)x[2 * pe], x1 = (float)x[2 * pe + 1];
    o[2 * pe]     = (__bf16)((x0 * cp[pe] - x1 * sp[pe]) * postscale);
    o[2 * pe + 1] = (__bf16)((x1 * cp[pe] + x0 * sp[pe]) * postscale);
  }
  return o;
}

// ---------------- fused assemble: qbuf (pre-scaled by QSC) / kbuf / v-transpose ----------------
__global__ void k_assemble(const bf16* __restrict__ q3, const bf16* __restrict__ kv,
                           const bf16* __restrict__ out1,
                           const float* __restrict__ cosT, const float* __restrict__ sinT,
                           bf16* __restrict__ qbuf, bf16* __restrict__ kbuf,
                           bf16* __restrict__ vt) {
  __shared__ bf16 tv[32][34];
  int blk = blockIdx.x;
  if (blk < 12288) {
    bool isQ = blk < 6144;
    int gid = (isQ ? blk : blk - 6144) * 256 + threadIdx.x;
    int rowIdx = gid / 24, pos = gid - rowIdx * 24;
    int d8 = pos * 8;
    int s = rowIdx & (SEQ - 1);
    int bhh = rowIdx >> 11;
    int hh = bhh & 15, b = bhh >> 4;
    size_t row = (size_t)b * SEQ + s;
    bf16x8 o;
    if (isQ) {
      if (d8 < HD) {
        bf16x8 x = *reinterpret_cast<const bf16x8*>(&q3[row * LDQ3 + hh * HD + d8]);
#pragma unroll
        for (int i = 0; i < 8; i++) o[i] = (__bf16)((float)x[i] * QSC);
      } else {
        int dd8 = d8 - HD;
        bf16x8 x = *reinterpret_cast<const bf16x8*>(&q3[row * LDQ3 + HID + hh * RD + dd8]);
        float4 c4 = *reinterpret_cast<const float4*>(&cosT[s * 32 + (dd8 >> 1)]);
        float4 s4 = *reinterpret_cast<const float4*>(&sinT[s * 32 + (dd8 >> 1)]);
        o = rope8(x, c4, s4, QSC);
      }
      *reinterpret_cast<bf16x8*>(&qbuf[(size_t)gid * 8]) = o;
    } else {
      if (d8 < HD) {
        o = *reinterpret_cast<const bf16x8*>(&kv[row * LDKV + hh * HD + d8]);
      } else {
        int dd8 = d8 - HD;
        bf16x8 x = *reinterpret_cast<const bf16x8*>(&out1[row * LDW1 + 1024 + dd8]);
        float4 c4 = *reinterpret_cast<const float4*>(&cosT[s * 32 + (dd8 >> 1)]);
        float4 s4 = *reinterpret_cast<const float4*>(&sinT[s * 32 + (dd8 >> 1)]);
        o = rope8(x, c4, s4, 1.0f);
      }
      *reinterpret_cast<bf16x8*>(&kbuf[(size_t)gid * 8]) = o;
    }
    return;
  }
  int local = blk - 12288;
  int dx = local & 3, sy = (local >> 2) & 63, bh = local >> 8;
  int b = bh >> 4, hh = bh & 15;
  int s0 = sy * 32, d0 = dx * 32;
  int c = threadIdx.x & 31, r0 = threadIdx.x >> 5;
#pragma unroll
  for (int i = 0; i < 32; i += 8)
    tv[r0 + i][c] = kv[((size_t)b * SEQ + s0 + r0 + i) * LDKV + HID + hh * HD + d0 + c];
  __syncthreads();
#pragma unroll
  for (int i = 0; i < 32; i += 8)
    vt[((size_t)bh * HD + d0 + r0 + i) * SEQ + s0 + c] = tv[c][r0 + i];
}

// ---------------- causal flash attention (R3 structure + exp2 domain + MFMA row-sum) ----------------
__global__ __launch_bounds__(256)
void k_attn(const bf16* __restrict__ Q, const bf16* __restrict__ Kb,
            const bf16* __restrict__ VT, bf16* __restrict__ Of) {
  constexpr int QB = 64, KBL = 64;
  __shared__ alignas(16) bf16 Ks[KBL * DQK];      // 24 KB, swizzled
  __shared__ alignas(16) bf16 Vs[HD * KBL];       // 16 KB, swizzled
  __shared__ alignas(16) bf16 Ps[4 * 16 * KBL];   // 8 KB, per-wave
  const int qt = (SEQ / QB - 1) - (blockIdx.x >> 5);  // longest-first
  const int bh = blockIdx.x & 31;
  const int b = bh >> 4, hh = bh & 15;
  const int tid = threadIdx.x, wave = tid >> 6, lane = tid & 63;
  const int lr = lane & 15, lk = lane >> 4;
  const int q0 = qt * QB;
  const int rb = wave * 16 + lk * 4;

  const bf16* Qp = Q + ((size_t)bh * SEQ + q0 + wave * 16 + lr) * DQK;
  bf16x8 qf[6];
#pragma unroll
  for (int c = 0; c < 6; c++)
    qf[c] = *reinterpret_cast<const bf16x8*>(Qp + c * 32 + lk * 8);

  // B-operand "ones column": D[q][0] = sum_k P[q][k]  (softmax denominator via MFMA)
  bf16x8 vones = {};
  if (lr == 0) {
#pragma unroll
    for (int i = 0; i < 8; i++) vones[i] = (__bf16)1.0f;
  }

  bf16* PsW = Ps + wave * (16 * KBL);

  f32x4 oacc[8] = {};
  f32x4 oaccL = {};  // denominator column, rescaled/accumulated like O
  float mrow[4];
#pragma unroll
  for (int r = 0; r < 4; r++) mrow[r] = -INFINITY;

  for (int kt = 0; kt <= qt; kt++) {
    const int k0 = kt * KBL;
    const bf16* Kbase = Kb + ((size_t)bh * SEQ + k0) * DQK;
    const bf16* Vbase = VT + (size_t)bh * HD * SEQ + k0;
    for (int c = wave; c < 24; c += 4) {
      int S = c * 64 + lane;
      int row = S / 24;
      int scl = (S - row * 24) ^ (row & 7);
      gload16(Kbase + row * DQK + scl * 8, (char*)Ks + c * 1024);
    }
    for (int c = wave; c < 16; c += 4) {
      int S = c * 64 + lane;
      int row = S >> 3;
      int scl = (S & 7) ^ (row & 7);
      gload16(Vbase + (size_t)row * SEQ + scl * 8, (char*)Vs + c * 1024);
    }
    __syncthreads();

    f32x4 sc[4] = {};
    __builtin_amdgcn_s_setprio(1);
#pragma unroll
    for (int cb = 0; cb < 4; cb++) {
      const int krow = cb * 16 + lr;
#pragma unroll
      for (int c = 0; c < 6; c++) {
        int phys = (c * 4 + lk) ^ (krow & 7);
        bf16x8 kf = *reinterpret_cast<const bf16x8*>(Ks + krow * DQK + phys * 8);
        sc[cb] = __builtin_amdgcn_mfma_f32_16x16x32_bf16(qf[c], kf, sc[cb], 0, 0, 0);
      }
    }
    __builtin_amdgcn_s_setprio(0);

    const bool maskit = (kt == qt);
    float p[4][4], tm[4];
#pragma unroll
    for (int r = 0; r < 4; r++) tm[r] = -INFINITY;
#pragma unroll
    for (int cb = 0; cb < 4; cb++) {
      const int kcg = k0 + cb * 16 + lr;
#pragma unroll
      for (int r = 0; r < 4; r++) {
        float v = sc[cb][r];  // already log2-domain (Q pre-scaled)
        if (maskit && kcg > q0 + rb + r) v = -INFINITY;
        p[cb][r] = v;
        tm[r] = fmaxf(tm[r], v);
      }
    }
#pragma unroll
    for (int m = 1; m < 16; m <<= 1)
#pragma unroll
      for (int r = 0; r < 4; r++) tm[r] = fmaxf(tm[r], __shfl_xor(tm[r], m, 16));

#pragma unroll
    for (int r = 0; r < 4; r++) {
      float mo = mrow[r];
      float mn = fmaxf(mo, tm[r]);
      if (tm[r] > mo) {  // exact defer: multiplier==1.0 -> skip rescale
        float al = exp2f(mo - mn);
        mrow[r] = mn;
        oaccL[r] *= al;
#pragma unroll
        for (int ocb = 0; ocb < 8; ocb++) oacc[ocb][r] *= al;
      }
#pragma unroll
      for (int cb = 0; cb < 4; cb++) p[cb][r] = exp2f(p[cb][r] - mn);
    }

    // P -> LDS (wave-private, swizzled)
#pragma unroll
    for (int cb = 0; cb < 4; cb++)
#pragma unroll
      for (int r = 0; r < 4; r++) {
        int prow = lk * 4 + r;
        int pslot = (cb * 2 + (lr >> 3)) ^ (prow & 7);
        PsW[prow * KBL + pslot * 8 + (lr & 7)] = f2bf(p[cb][r]);
      }

    __builtin_amdgcn_s_setprio(1);
#pragma unroll
    for (int kk = 0; kk < 2; kk++) {
      int pphys = (kk * 4 + lk) ^ (lr & 7);
      bf16x8 pa = *reinterpret_cast<const bf16x8*>(PsW + lr * KBL + pphys * 8);
      oaccL = __builtin_amdgcn_mfma_f32_16x16x32_bf16(pa, vones, oaccL, 0, 0, 0);
#pragma unroll
      for (int ocb = 0; ocb < 8; ocb++) {
        int vrow = ocb * 16 + lr;
        int vphys = (kk * 4 + lk) ^ (vrow & 7);
        bf16x8 vb = *reinterpret_cast<const bf16x8*>(Vs + vrow * KBL + vphys * 8);
        oacc[ocb] = __builtin_amdgcn_mfma_f32_16x16x32_bf16(pa, vb, oacc[ocb], 0, 0, 0);
      }
    }
    __builtin_amdgcn_s_setprio(0);
    __syncthreads();
  }

  // broadcast denominator (held by lr==0 lanes) to the 16-lane row group
  float linv[4];
#pragma unroll
  for (int r = 0; r < 4; r++) {
    float l = __shfl(oaccL[r], lane & 48);
    linv[r] = 1.0f / l;
  }

#pragma unroll
  for (int ocb = 0; ocb < 8; ocb++)
#pragma unroll
    for (int r = 0; r < 4; r++) {
      int qr = q0 + rb + r;
      float v = oacc[ocb][r] * linv[r];
      Of[((size_t)b * SEQ + qr) * HID + hh * HD + ocb * 16 + lr] = f2bf(v);
    }
}

// ---------------- host launch ----------------
extern "C" void kernel_launch(void* const* d_in, const int* in_sizes, int n_in,
                              void* d_out, int out_size, void* d_ws, size_t ws_size,
                              hipStream_t stream) {
  const float* h    = (const float*)d_in[0];
  const float* Wdkv = (const float*)d_in[1];
  const float* Wuk  = (const float*)d_in[2];
  const float* Wkr  = (const float*)d_in[3];
  const float* Wuv  = (const float*)d_in[4];
  const float* Wdq  = (const float*)d_in[5];
  const float* Wuq  = (const float*)d_in[6];
  const float* Wqr  = (const float*)d_in[7];
  const float* Wo   = (const float*)d_in[8];
  float* out = (float*)d_out;

  char* w = (char*)d_ws;
  auto alloc = [&](size_t elems) {
    bf16* p = (bf16*)w;
    w += (elems * sizeof(bf16) + 255) & ~(size_t)255;
    return p;
  };
  bf16* hb   = alloc((size_t)MR * HID);
  bf16* wt1  = alloc((size_t)LDW1 * HID);
  bf16* wt2  = alloc((size_t)LDKV * LAT);
  bf16* wt3  = alloc((size_t)LDQ3 * LAT);
  bf16* woT  = alloc((size_t)HID * HID);
  bf16* out1 = alloc((size_t)MR * LDW1);
  bf16* kv   = alloc((size_t)MR * LDKV);
  bf16* q3   = alloc((size_t)MR * LDQ3);
  bf16* qbuf = alloc((size_t)BB * NHEAD * SEQ * DQK);
  bf16* kbuf = alloc((size_t)BB * NHEAD * SEQ * DQK);
  bf16* vt   = alloc((size_t)BB * NHEAD * HD * SEQ);
  bf16* oflat= alloc((size_t)MR * HID);
  float* cosT = (float*)alloc((size_t)SEQ * 32 * 2);
  float* sinT = (float*)alloc((size_t)SEQ * 32 * 2);

  // 1) all prep (weights, rope, h->bf16)
  k_prep<<<18304, 256, 0, stream>>>(h, Wdkv, Wdq, Wkr, Wuk, Wuv, Wuq, Wqr, Wo,
                                    hb, wt1, wt2, wt3, woT, cosT, sinT);
  // 2) fused proj-1: out1 = hb @ [Wdkv|Wdq|Wkr]
  k_gemm_bt<128, 128, bf16><<<dim3(LDW1 / 128, MR / 128), 256, 0, stream>>>(hb, HID, wt1, out1, LDW1, HID);
  // 3) fused proj-2/3: kv = ckv @ [Wuk|Wuv]; q3 = cq @ [Wuq|Wqr]
  k_gemm23<<<dim3((LDKV + LDQ3) / 128, MR / 128), 256, 0, stream>>>(out1, wt2, wt3, kv, q3);
  // 4) assemble q/k (rope, Q pre-scaled) + v transpose
  k_assemble<<<20480, 256, 0, stream>>>(q3, kv, out1, cosT, sinT, qbuf, kbuf, vt);
  // 5) attention (longest-first, R3 structure + exp2 + MFMA row-sum)
  k_attn<<<(SEQ / 64) * 32, 256, 0, stream>>>(qbuf, kbuf, vt, oflat);
  // 6) output projection
  k_gemm_bt<128, 128, float><<<dim3(HID / 128, MR / 128), 256, 0, stream>>>(oflat, HID, woT, out, HID, HID);
}